// Round 8
// baseline (169.364 us; speedup 1.0000x reference)
//
#include <hip/hip_runtime.h>

#define Bsz  4
#define Tseq 2048
#define Cdim 512
#define Hn   8
#define Dh   64
#define BT   8192     // Bsz*Tseq tokens
#define NQKV 1536
#define NEG_BIG (-1e30f)

typedef __attribute__((ext_vector_type(8))) short bf16x8;  // 8 bf16 = 4 VGPRs
typedef __attribute__((ext_vector_type(4))) short bf16x4;  // 4 bf16 = 2 VGPRs
typedef __attribute__((ext_vector_type(4))) float f32x4;

__device__ __forceinline__ float b2f(short s) {
    unsigned u = ((unsigned)(unsigned short)s) << 16;
    float f; __builtin_memcpy(&f, &u, 4); return f;
}
__device__ __forceinline__ short f2b(float f) {
    unsigned u; __builtin_memcpy(&u, &f, 4);
    u = (u + 0x7fffu + ((u >> 16) & 1u)) >> 16;   // RNE
    return (short)u;
}
// async global->LDS, 16B/lane; LDS dest = wave-uniform base + lane*16
__device__ __forceinline__ void g2l16(const short* g, short* l) {
    __builtin_amdgcn_global_load_lds(
        (const __attribute__((address_space(1))) unsigned int*)(uintptr_t)g,
        (__attribute__((address_space(3))) unsigned int*)l, 16, 0, 0);
}

// ---------------- prep: fused weight transpose (blocks 0..255) + LayerNorm1 (blocks 256..2303) ----------------
__global__ __launch_bounds__(256) void k_prep(const float* __restrict__ wq, const float* __restrict__ wk,
                                              const float* __restrict__ wv, const float* __restrict__ wff,
                                              short* __restrict__ wqkvt, short* __restrict__ wfft,
                                              const float* __restrict__ x, const float* __restrict__ g,
                                              const float* __restrict__ b, short* __restrict__ out) {
    const int blk = blockIdx.x, tid = threadIdx.x;
    if (blk < 256) {
        __shared__ float ldsT[64 * 65];          // 64x64 tile, pad 65: conflict-free both phases
        if (blk < 192) {                         // QKV heads: per-head 512x64 -> 64x512
            int hm = blk >> 3, ct = blk & 7;
            int proj = hm >> 3, h = hm & 7;
            const float* w = (proj == 0) ? wq : (proj == 1 ? wk : wv);
#pragma unroll
            for (int i = 0; i < 16; i++) {
                int flat = i * 256 + tid, cc = flat >> 6, dd = flat & 63;
                ldsT[dd * 65 + cc] = w[(h * 512 + ct * 64 + cc) * 64 + dd];   // coalesced in dd
            }
            __syncthreads();
#pragma unroll
            for (int i = 0; i < 16; i++) {
                int flat = i * 256 + tid, dd = flat >> 6, cc = flat & 63;
                int n = proj * 512 + h * 64 + dd;
                wqkvt[n * 512 + ct * 64 + cc] = f2b(ldsT[dd * 65 + cc]);      // coalesced in cc
            }
        } else {                                 // FF: 512x512 -> 512x512 transposed
            int b2 = blk - 192, rt = b2 >> 3, nt8 = b2 & 7;
#pragma unroll
            for (int i = 0; i < 16; i++) {
                int flat = i * 256 + tid, cc = flat >> 6, nn = flat & 63;
                ldsT[nn * 65 + cc] = wff[(rt * 64 + cc) * 512 + nt8 * 64 + nn];
            }
            __syncthreads();
#pragma unroll
            for (int i = 0; i < 16; i++) {
                int flat = i * 256 + tid, nn = flat >> 6, cc = flat & 63;
                wfft[(nt8 * 64 + nn) * 512 + rt * 64 + cc] = f2b(ldsT[nn * 65 + cc]);
            }
        }
    } else {                                     // LayerNorm1: one wave per token row
        int row  = (blk - 256) * 4 + (tid >> 6);
        int lane = tid & 63;
        const f32x4 a0 = *(const f32x4*)(x + row * Cdim + lane * 8);
        const f32x4 a1 = *(const f32x4*)(x + row * Cdim + lane * 8 + 4);
        float v[8] = {a0[0], a0[1], a0[2], a0[3], a1[0], a1[1], a1[2], a1[3]};
        float s = 0.f, sq = 0.f;
#pragma unroll
        for (int i = 0; i < 8; i++) { s += v[i]; sq += v[i] * v[i]; }
#pragma unroll
        for (int off = 1; off < 64; off <<= 1) { s += __shfl_xor(s, off); sq += __shfl_xor(sq, off); }
        float mean = s * (1.f / 512.f);
        float var  = sq * (1.f / 512.f) - mean * mean;
        float rstd = rsqrtf(var + 1e-5f);
        const f32x4 g0 = *(const f32x4*)(g + lane * 8);
        const f32x4 g1 = *(const f32x4*)(g + lane * 8 + 4);
        const f32x4 b0 = *(const f32x4*)(b + lane * 8);
        const f32x4 b1 = *(const f32x4*)(b + lane * 8 + 4);
        float gg[8] = {g0[0], g0[1], g0[2], g0[3], g1[0], g1[1], g1[2], g1[3]};
        float bb[8] = {b0[0], b0[1], b0[2], b0[3], b1[0], b1[1], b1[2], b1[3]};
        bf16x8 o;
#pragma unroll
        for (int i = 0; i < 8; i++) o[i] = f2b((v[i] - mean) * rstd * gg[i] + bb[i]);
        *(bf16x8*)(out + row * Cdim + lane * 8) = o;
    }
}

// ---------------- LayerNorm (standalone, for LN2): fp32 in, bf16 out ----------------
__global__ __launch_bounds__(256) void k_ln(const float* __restrict__ x, const float* __restrict__ g,
                                            const float* __restrict__ b, short* __restrict__ out) {
    int row  = blockIdx.x * 4 + (threadIdx.x >> 6);
    int lane = threadIdx.x & 63;
    const f32x4 a0 = *(const f32x4*)(x + row * Cdim + lane * 8);
    const f32x4 a1 = *(const f32x4*)(x + row * Cdim + lane * 8 + 4);
    float v[8] = {a0[0], a0[1], a0[2], a0[3], a1[0], a1[1], a1[2], a1[3]};
    float s = 0.f, sq = 0.f;
#pragma unroll
    for (int i = 0; i < 8; i++) { s += v[i]; sq += v[i] * v[i]; }
#pragma unroll
    for (int off = 1; off < 64; off <<= 1) { s += __shfl_xor(s, off); sq += __shfl_xor(sq, off); }
    float mean = s * (1.f / 512.f);
    float var  = sq * (1.f / 512.f) - mean * mean;
    float rstd = rsqrtf(var + 1e-5f);
    const f32x4 g0 = *(const f32x4*)(g + lane * 8);
    const f32x4 g1 = *(const f32x4*)(g + lane * 8 + 4);
    const f32x4 b0 = *(const f32x4*)(b + lane * 8);
    const f32x4 b1 = *(const f32x4*)(b + lane * 8 + 4);
    float gg[8] = {g0[0], g0[1], g0[2], g0[3], g1[0], g1[1], g1[2], g1[3]};
    float bb[8] = {b0[0], b0[1], b0[2], b0[3], b1[0], b1[1], b1[2], b1[3]};
    bf16x8 o;
#pragma unroll
    for (int i = 0; i < 8; i++) o[i] = f2b((v[i] - mean) * rstd * gg[i] + bb[i]);
    *(bf16x8*)(out + row * Cdim + lane * 8) = o;
}

// ---------------- QKV GEMM v6: 128x64 tile, 6 blocks/CU, counted-vmcnt + LDS-transpose vt ----------------
// Round-18: session evidence says latency/residency-bound (2-phase helped, vmcnt-count
// neutral, occupancy drops always regressed). 128x128 was grid-capped at 3 blocks/CU;
// 128x64 -> 1536 blocks = 6/CU (LDS 24KB, 24 waves/CU). Batch = 3 loads -> vmcnt(3).
__global__ __launch_bounds__(256) void k_gemm_qkv(const short* __restrict__ A, const short* __restrict__ Wt,
                                                  short* __restrict__ q, short* __restrict__ k,
                                                  short* __restrict__ vt) {
    const int tid = threadIdx.x;
    const int wave = tid >> 6, lane = tid & 63;
    const int quad = lane >> 4, l15 = lane & 15;
    const int m0 = blockIdx.x * 128, n0 = blockIdx.y * 64;
    const int wm = wave & 1, wn = wave >> 1;       // m-half 64, n-half 32
    __shared__ __align__(16) short smem[12288];    // 24KB: As[2][128*32] | Bs[2][64*32]; Tw unions
    short* As = smem;                              // + buf*4096
    short* Bs = smem + 8192;                       // + buf*2048
    f32x4 acc[4][2];
#pragma unroll
    for (int i = 0; i < 4; i++)
#pragma unroll
        for (int j = 0; j < 2; j++) acc[i][j] = (f32x4){0.f, 0.f, 0.f, 0.f};
    const int lr = lane >> 2, lc = lane & 3;       // staging: row = lane/4, 16B-col = lane%4
    const short* Ag = A  + (m0 + wave * 32 + lr) * Cdim + lc * 8;   // 32 A-rows/wave: 2 calls
    const short* Bg = Wt + (n0 + wave * 16 + lr) * Cdim + lc * 8;   // 16 B-rows/wave: 1 call
    // prologue: stage batches 0 and 1 (3 loads each, in order)
    g2l16(Ag,                  As + wave * 1024);
    g2l16(Ag + 16 * Cdim,      As + wave * 1024 + 512);
    g2l16(Bg,                  Bs + wave * 512);
    g2l16(Ag + 32,             As + 4096 + wave * 1024);
    g2l16(Ag + 16 * Cdim + 32, As + 4096 + wave * 1024 + 512);
    g2l16(Bg + 32,             Bs + 2048 + wave * 512);
    for (int kk = 0; kk < 16; kk++) {
        const int cur = kk & 1;
        if (kk < 15) { asm volatile("s_waitcnt vmcnt(3)" ::: "memory"); }   // oldest batch landed
        else         { asm volatile("s_waitcnt vmcnt(0)" ::: "memory"); }
        __builtin_amdgcn_s_barrier();              // buf[cur] ready across all waves
        __builtin_amdgcn_sched_barrier(0);
        bf16x8 a[4], w[2];
#pragma unroll
        for (int mt = 0; mt < 4; mt++) a[mt] = *(const bf16x8*)(As + cur * 4096 + (wm * 64 + mt * 16 + l15) * 32 + quad * 8);
#pragma unroll
        for (int nt = 0; nt < 2; nt++) w[nt] = *(const bf16x8*)(Bs + cur * 2048 + (wn * 32 + nt * 16 + l15) * 32 + quad * 8);
#pragma unroll
        for (int mt = 0; mt < 4; mt++)
#pragma unroll
            for (int nt = 0; nt < 2; nt++)
                acc[mt][nt] = __builtin_amdgcn_mfma_f32_16x16x32_bf16(a[mt], w[nt], acc[mt][nt], 0, 0, 0);
        __builtin_amdgcn_sched_barrier(0);
        __builtin_amdgcn_s_barrier();              // all waves done reading buf[cur]
        if (kk + 2 < 16) {                         // refill the just-freed buffer
            const int k0 = (kk + 2) * 32;
            g2l16(Ag + k0,             As + cur * 4096 + wave * 1024);
            g2l16(Ag + 16 * Cdim + k0, As + cur * 4096 + wave * 1024 + 512);
            g2l16(Bg + k0,             Bs + cur * 2048 + wave * 512);
        }
    }
    // epilogue: n-tile (64) = exactly one head; proj block-uniform
    const int proj = n0 >> 9;
    const int hh   = (n0 & 511) >> 6;
    const int m0w  = m0 + wm * 64;
    if (proj < 2) {                                // q/k: row-major, coalesced enough
#pragma unroll
        for (int mt = 0; mt < 4; mt++) {
#pragma unroll
            for (int r = 0; r < 4; r++) {
                int t  = m0w + mt * 16 + quad * 4 + r;
                int bi = t >> 11, tt = t & 2047;
#pragma unroll
                for (int nt = 0; nt < 2; nt++) {
                    int d = wn * 32 + nt * 16 + l15;
                    short val = f2b(acc[mt][nt][r]);
                    if (proj == 0) q[((bi * Hn + hh) * Tseq + tt) * Dh + d] = val;
                    else           k[((bi * Hn + hh) * Tseq + tt) * Dh + d] = val;
                }
            }
        }
    } else {                                       // vt: transpose through wave-private LDS
        short* Tw = smem + wave * 2176;            // 32 d-rows x 68 stride (post-loop reuse safe)
#pragma unroll
        for (int mt = 0; mt < 4; mt++)
#pragma unroll
            for (int nt = 0; nt < 2; nt++) {
                bf16x4 pk;
#pragma unroll
                for (int r = 0; r < 4; r++) pk[r] = f2b(acc[mt][nt][r]);
                *(bf16x4*)(Tw + (nt * 16 + l15) * 68 + mt * 16 + quad * 4) = pk;
            }
        asm volatile("s_waitcnt lgkmcnt(0)" ::: "memory");   // wave-private: no barrier needed
        const int bi = m0 >> 11, tt0 = m0w & 2047;
        const int g8 = lane >> 3, h8 = lane & 7;   // 8 d-rows per pass, 16B slot within row
        short* vbase = vt + ((size_t)((bi * Hn + hh) * Dh) + wn * 32) * Tseq;
#pragma unroll
        for (int p = 0; p < 4; p++) {
            int dl = p * 8 + g8;
            bf16x8 row = *(const bf16x8*)(Tw + dl * 68 + h8 * 8);
            *(bf16x8*)(vbase + (size_t)dl * Tseq + tt0 + h8 * 8) = row;   // 128B/row coalesced
        }
    }
}

// ---------------- causal flash attention v12c: v12b + s_setprio around MFMA clusters (T5) ----------------
__global__ __launch_bounds__(256, 3) void k_attn(const short* __restrict__ qb, const short* __restrict__ kb,
                                                 const short* __restrict__ vtb, const float* __restrict__ x,
                                                 float* __restrict__ out1) {
    const int wave = threadIdx.x >> 6, lane = threadIdx.x & 63;
    const int quad = lane >> 4, l15 = lane & 15;
    const int D  = blockIdx.y * 32 + blockIdx.x;           // linear dispatch id
    const int j5 = D & 31;
    const int bh = (j5 & 7) * 4 + (j5 >> 3);               // XCD (D&7) -> bh group affinity
    const int u  = D >> 5, kq = u >> 3, d8 = u & 7;
    const int qg = (kq == 0) ? 31 - d8 : (kq == 1) ? 16 + d8 : (kq == 2) ? 15 - d8 : d8;
    const int q0  = qg * 64;                               // block's 64 q-rows
    const int qw0 = q0 + wave * 16;                        // this wave's 16 q-rows
    const int nkt = qg + 1;                                // 64-key tiles (keys <= q0+63)

    const short* Q = qb  + bh * Tseq * Dh;
    const short* K = kb  + bh * Tseq * Dh;
    const short* V = vtb + bh * Dh * Tseq;                 // [d][s]

    __shared__ __align__(16) short Ks[2][64 * 64];         // [key][d], XOR-swizzled cols
    __shared__ __align__(16) short Vs[2][64 * 64];         // [d][s],  XOR-swizzled cols
    __shared__ __align__(16) short Ps[4][16 * 72];         // per-wave P tile [q][s] stride 72
    short* pw = &Ps[wave][0];

    // staging geometry: call covers 8 rows x 128B; lane L -> row lr8, 16B slot lc8^lr8
    const int lr8 = lane >> 3, lc8 = lane & 7;
    const int sw8 = (lc8 ^ lr8) << 3;                      // pre-swizzled source col (shorts)
    const short* Ksrc = K + (wave * 16 + lr8) * Dh + sw8;  // wave stages K rows 16w..16w+15
    const short* Vsrc = V + (wave * 16 + lr8) * Tseq + sw8;// wave stages V d-rows 16w..16w+15

    // prologue: stage tile 0 into buf 0
    g2l16(Ksrc,            &Ks[0][wave * 1024]);
    g2l16(Ksrc + 8 * Dh,   &Ks[0][wave * 1024 + 512]);
    g2l16(Vsrc,            &Vs[0][wave * 1024]);
    g2l16(Vsrc + 8 * Tseq, &Vs[0][wave * 1024 + 512]);

    bf16x8 qa[2];
#pragma unroll
    for (int c = 0; c < 2; c++)
        qa[c] = *(const bf16x8*)(Q + (qw0 + l15) * Dh + c * 32 + quad * 8);

    f32x4 o[4];
#pragma unroll
    for (int i = 0; i < 4; i++) o[i] = (f32x4){0.f, 0.f, 0.f, 0.f};
    float m_i = NEG_BIG, l_i = 0.f;                        // per-lane: q-row = qw0 + l15

    const float sc = 0.125f * 1.44269504089f;              // scale * log2(e)
    const int sx = l15 & 7;                                // read-side swizzle (row&7)

    __syncthreads();                                       // tile 0 staged (drains vmcnt)

    for (int kt = 0; kt < nkt; kt++) {
        const short* Kb = &Ks[kt & 1][0];
        const short* Vb = &Vs[kt & 1][0];
        if (kt + 1 < nkt) {                                // stage next tile into other buf
            g2l16(Ksrc + (kt + 1) * 64 * Dh,            &Ks[(kt + 1) & 1][wave * 1024]);
            g2l16(Ksrc + (kt + 1) * 64 * Dh + 8 * Dh,   &Ks[(kt + 1) & 1][wave * 1024 + 512]);
            g2l16(Vsrc + (kt + 1) * 64,                 &Vs[(kt + 1) & 1][wave * 1024]);
            g2l16(Vsrc + (kt + 1) * 64 + 8 * Tseq,      &Vs[(kt + 1) & 1][wave * 1024 + 512]);
        }
        const int s0 = kt * 64;
        // ---- QK^T from LDS (swizzled reads) ----
        f32x4 st[4];
        __builtin_amdgcn_s_setprio(1);
#pragma unroll
        for (int nt = 0; nt < 4; nt++) {
            bf16x8 k0 = *(const bf16x8*)(Kb + (nt * 16 + l15) * 64 + ((quad ^ sx) << 3));
            bf16x8 k1 = *(const bf16x8*)(Kb + (nt * 16 + l15) * 64 + (((4 | quad) ^ sx) << 3));
            f32x4 z = (f32x4){0.f, 0.f, 0.f, 0.f};
            z = __builtin_amdgcn_mfma_f32_16x16x32_bf16(k0, qa[0], z, 0, 0, 0);
            z = __builtin_amdgcn_mfma_f32_16x16x32_bf16(k1, qa[1], z, 0, 0, 0);
            st[nt] = z;
        }
        __builtin_amdgcn_s_setprio(0);
        // ---- mask + scale (only the last tile crosses the diagonal for every wave) ----
        const int qq = qw0 + l15;
        if (kt == nkt - 1) {
#pragma unroll
            for (int nt = 0; nt < 4; nt++)
#pragma unroll
                for (int r = 0; r < 4; r++) {
                    int s = s0 + nt * 16 + quad * 4 + r;
                    st[nt][r] = (s > qq) ? NEG_BIG : st[nt][r] * sc;
                }
        } else {
#pragma unroll
            for (int nt = 0; nt < 4; nt++)
#pragma unroll
                for (int r = 0; r < 4; r++) st[nt][r] *= sc;
        }
        // ---- online softmax with defer-max (THR=8, wave-uniform skip) ----
        float mx = fmaxf(fmaxf(fmaxf(st[0][0], st[0][1]), fmaxf(st[0][2], st[0][3])),
                         fmaxf(fmaxf(st[1][0], st[1][1]), fmaxf(st[1][2], st[1][3])));
        mx = fmaxf(mx, fmaxf(fmaxf(fmaxf(st[2][0], st[2][1]), fmaxf(st[2][2], st[2][3])),
                             fmaxf(fmaxf(st[3][0], st[3][1]), fmaxf(st[3][2], st[3][3]))));
        mx = fmaxf(mx, __shfl_xor(mx, 16));
        mx = fmaxf(mx, __shfl_xor(mx, 32));
        if (!__all(mx <= m_i + 8.f)) {             // rescale only on significant max growth
            float mn    = fmaxf(m_i, mx);
            float alpha = __builtin_amdgcn_exp2f(m_i - mn);
            m_i = mn;
            l_i *= alpha;
#pragma unroll
            for (int r = 0; r < 4; r++) {
                float ar = __shfl(alpha, quad * 4 + r);
#pragma unroll
                for (int dt = 0; dt < 4; dt++) o[dt][r] *= ar;
            }
        }
        float rs = 0.f;
        bf16x4 pk[4];
#pragma unroll
        for (int nt = 0; nt < 4; nt++) {
#pragma unroll
            for (int r = 0; r < 4; r++) {
                float p = __builtin_amdgcn_exp2f(st[nt][r] - m_i);   // masked -> 0; bounded 2^8
                rs += p;
                pk[nt][r] = f2b(p);
            }
        }
        rs += __shfl_xor(rs, 16);
        rs += __shfl_xor(rs, 32);
        l_i += rs;
#pragma unroll
        for (int nt = 0; nt < 4; nt++)
            *(bf16x4*)(pw + l15 * 72 + nt * 16 + quad * 4) = pk[nt];
        asm volatile("s_waitcnt lgkmcnt(0)" ::: "memory");
        bf16x8 pa[2];
#pragma unroll
        for (int c = 0; c < 2; c++)
            pa[c] = *(const bf16x8*)(pw + l15 * 72 + c * 32 + quad * 8);
        // ---- PV from LDS V (swizzled reads) ----
        __builtin_amdgcn_s_setprio(1);
#pragma unroll
        for (int c = 0; c < 2; c++)
#pragma unroll
            for (int v4 = 0; v4 < 4; v4++) {
                bf16x8 vb = *(const bf16x8*)(Vb + (v4 * 16 + l15) * 64 + ((((c << 2) | quad) ^ sx) << 3));
                o[v4] = __builtin_amdgcn_mfma_f32_16x16x32_bf16(pa[c], vb, o[v4], 0, 0, 0);
            }
        __builtin_amdgcn_s_setprio(0);
        __syncthreads();    // waves done reading buf[kt&1]; staged tile kt+1 complete (vmcnt)
    }
    // ---- per-wave epilogue: rows qw0..qw0+15, no cross-wave combine ----
    const int bi = bh >> 3, hh = bh & 7;
#pragma unroll
    for (int r = 0; r < 4; r++) {
        int row = quad * 4 + r;
        float Lr  = __shfl(l_i, row);              // l_i uniform across the 4 quads per l15
        float inv = 1.f / Lr;
#pragma unroll
        for (int v4 = 0; v4 < 4; v4++) {
            int t   = qw0 + row;
            int idx = (bi * Tseq + t) * Cdim + hh * Dh + v4 * 16 + l15;
            out1[idx] = x[idx] + o[v4][r] * inv;
        }
    }
}

// ---------------- FF GEMM v5: 64x64 tile, 4 blocks/CU, counted-vmcnt pipeline ----------------
// Round-18: 128x64 was grid-capped at 2 blocks/CU; 64x64 -> 1024 blocks = 4/CU (LDS 16KB).
// Batch = 2 loads -> vmcnt(2).
__global__ __launch_bounds__(256) void k_gemm_ff(const short* __restrict__ A, const short* __restrict__ Wt,
                                                 const float* __restrict__ bias, const float* __restrict__ res,
                                                 float* __restrict__ out) {
    const int tid = threadIdx.x;
    const int wave = tid >> 6, lane = tid & 63;
    const int quad = lane >> 4, l15 = lane & 15;
    const int m0 = blockIdx.x * 64, n0 = blockIdx.y * 64;
    const int wm = wave & 1, wn = wave >> 1;           // wave -> 32-row half, 32-col half
    __shared__ __align__(16) short As[2][64 * 32];     // 4 KB per buf
    __shared__ __align__(16) short Bs[2][64 * 32];
    f32x4 acc[2][2];
#pragma unroll
    for (int i = 0; i < 2; i++)
#pragma unroll
        for (int j = 0; j < 2; j++) acc[i][j] = (f32x4){0.f, 0.f, 0.f, 0.f};
    const int lr = lane >> 2, lc = lane & 3;           // 16 rows x 4 slots per g2l16 call
    const short* Ag = A  + (m0 + wave * 16 + lr) * Cdim + lc * 8;   // 16 A-rows/wave: 1 call
    const short* Bg = Wt + (n0 + wave * 16 + lr) * Cdim + lc * 8;   // 16 B-rows/wave: 1 call
    // prologue: stage batches 0 and 1 (2 loads each, in order)
    g2l16(Ag,       &As[0][wave * 512]);
    g2l16(Bg,       &Bs[0][wave * 512]);
    g2l16(Ag + 32,  &As[1][wave * 512]);
    g2l16(Bg + 32,  &Bs[1][wave * 512]);
    for (int kk = 0; kk < 16; kk++) {
        const int cur = kk & 1;
        if (kk < 15) { asm volatile("s_waitcnt vmcnt(2)" ::: "memory"); }   // oldest batch landed
        else         { asm volatile("s_waitcnt vmcnt(0)" ::: "memory"); }
        __builtin_amdgcn_s_barrier();              // buf[cur] ready across all waves
        __builtin_amdgcn_sched_barrier(0);
        bf16x8 a[2], w[2];
#pragma unroll
        for (int mt = 0; mt < 2; mt++) a[mt] = *(const bf16x8*)(&As[cur][(wm * 32 + mt * 16 + l15) * 32 + quad * 8]);
#pragma unroll
        for (int nt = 0; nt < 2; nt++) w[nt] = *(const bf16x8*)(&Bs[cur][(wn * 32 + nt * 16 + l15) * 32 + quad * 8]);
#pragma unroll
        for (int mt = 0; mt < 2; mt++)
#pragma unroll
            for (int nt = 0; nt < 2; nt++)
                acc[mt][nt] = __builtin_amdgcn_mfma_f32_16x16x32_bf16(a[mt], w[nt], acc[mt][nt], 0, 0, 0);
        __builtin_amdgcn_sched_barrier(0);
        __builtin_amdgcn_s_barrier();              // all waves done reading buf[cur]
        if (kk + 2 < 16) {                         // refill the just-freed buffer
            const int k0 = (kk + 2) * 32;
            g2l16(Ag + k0, &As[cur][wave * 512]);
            g2l16(Bg + k0, &Bs[cur][wave * 512]);
        }
    }
    const int m0w = m0 + wm * 32, n0w = n0 + wn * 32;
#pragma unroll
    for (int mt = 0; mt < 2; mt++) {
#pragma unroll
        for (int r = 0; r < 4; r++) {
            int t = m0w + mt * 16 + quad * 4 + r;
#pragma unroll
            for (int nt = 0; nt < 2; nt++) {
                int n = n0w + nt * 16 + l15;
                float fv = acc[mt][nt][r] + bias[n];
                fv = fmaxf(fv, 0.f);
                out[t * Cdim + n] = res[t * Cdim + n] + fv;
            }
        }
    }
}

extern "C" void kernel_launch(void* const* d_in, const int* in_sizes, int n_in,
                              void* d_out, int out_size, void* d_ws, size_t ws_size,
                              hipStream_t stream) {
    const float* x   = (const float*)d_in[0];
    const float* wq  = (const float*)d_in[1];
    const float* wk  = (const float*)d_in[2];
    const float* wv  = (const float*)d_in[3];
    const float* wff = (const float*)d_in[4];
    const float* bff = (const float*)d_in[5];
    const float* g1  = (const float*)d_in[6];
    const float* b1  = (const float*)d_in[7];
    const float* g2  = (const float*)d_in[8];
    const float* b2  = (const float*)d_in[9];

    char* p = (char*)d_ws;                                  // ~50 MB total scratch
    short* wqkvt = (short*)p; p += (size_t)NQKV * Cdim * 2;
    short* wfft  = (short*)p; p += (size_t)Cdim * Cdim * 2;
    short* h1    = (short*)p; p += (size_t)BT * Cdim * 2;   // reused as h2 after attention
    short* qb    = (short*)p; p += (size_t)BT * Cdim * 2;
    short* kb    = (short*)p; p += (size_t)BT * Cdim * 2;
    short* vtb   = (short*)p; p += (size_t)BT * Cdim * 2;
    float* out1  = (float*)p; p += (size_t)BT * Cdim * 4;

    hipLaunchKernelGGL(k_prep,     dim3(2304),    dim3(256), 0, stream,
                       wq, wk, wv, wff, wqkvt, wfft, x, g1, b1, h1);
    hipLaunchKernelGGL(k_gemm_qkv, dim3(64, 24),  dim3(256), 0, stream, h1, wqkvt, qb, kb, vtb);
    hipLaunchKernelGGL(k_attn,     dim3(32, 32),  dim3(256), 0, stream, qb, kb, vtb, x, out1);
    hipLaunchKernelGGL(k_ln,       dim3(2048),    dim3(256), 0, stream, out1, g2, b2, h1);
    hipLaunchKernelGGL(k_gemm_ff,  dim3(128, 8),  dim3(256), 0, stream, h1, wfft, bff, out1, (float*)d_out);
}

// Round 9
// 165.196 us; speedup vs baseline: 1.0252x; 1.0252x over previous
//
#include <hip/hip_runtime.h>

#define Bsz  4
#define Tseq 2048
#define Cdim 512
#define Hn   8
#define Dh   64
#define BT   8192     // Bsz*Tseq tokens
#define NQKV 1536
#define NEG_BIG (-1e30f)

typedef __attribute__((ext_vector_type(8))) short bf16x8;  // 8 bf16 = 4 VGPRs
typedef __attribute__((ext_vector_type(4))) short bf16x4;  // 4 bf16 = 2 VGPRs
typedef __attribute__((ext_vector_type(4))) float f32x4;

__device__ __forceinline__ float b2f(short s) {
    unsigned u = ((unsigned)(unsigned short)s) << 16;
    float f; __builtin_memcpy(&f, &u, 4); return f;
}
__device__ __forceinline__ short f2b(float f) {
    unsigned u; __builtin_memcpy(&u, &f, 4);
    u = (u + 0x7fffu + ((u >> 16) & 1u)) >> 16;   // RNE
    return (short)u;
}
// async global->LDS, 16B/lane; LDS dest = wave-uniform base + lane*16
__device__ __forceinline__ void g2l16(const short* g, short* l) {
    __builtin_amdgcn_global_load_lds(
        (const __attribute__((address_space(1))) unsigned int*)(uintptr_t)g,
        (__attribute__((address_space(3))) unsigned int*)l, 16, 0, 0);
}

// ---------------- prep: fused weight transpose (blocks 0..255) + LayerNorm1 (blocks 256..2303) ----------------
__global__ __launch_bounds__(256) void k_prep(const float* __restrict__ wq, const float* __restrict__ wk,
                                              const float* __restrict__ wv, const float* __restrict__ wff,
                                              short* __restrict__ wqkvt, short* __restrict__ wfft,
                                              const float* __restrict__ x, const float* __restrict__ g,
                                              const float* __restrict__ b, short* __restrict__ out) {
    const int blk = blockIdx.x, tid = threadIdx.x;
    if (blk < 256) {
        __shared__ float ldsT[64 * 65];          // 64x64 tile, pad 65: conflict-free both phases
        if (blk < 192) {                         // QKV heads: per-head 512x64 -> 64x512
            int hm = blk >> 3, ct = blk & 7;
            int proj = hm >> 3, h = hm & 7;
            const float* w = (proj == 0) ? wq : (proj == 1 ? wk : wv);
#pragma unroll
            for (int i = 0; i < 16; i++) {
                int flat = i * 256 + tid, cc = flat >> 6, dd = flat & 63;
                ldsT[dd * 65 + cc] = w[(h * 512 + ct * 64 + cc) * 64 + dd];   // coalesced in dd
            }
            __syncthreads();
#pragma unroll
            for (int i = 0; i < 16; i++) {
                int flat = i * 256 + tid, dd = flat >> 6, cc = flat & 63;
                int n = proj * 512 + h * 64 + dd;
                wqkvt[n * 512 + ct * 64 + cc] = f2b(ldsT[dd * 65 + cc]);      // coalesced in cc
            }
        } else {                                 // FF: 512x512 -> 512x512 transposed
            int b2 = blk - 192, rt = b2 >> 3, nt8 = b2 & 7;
#pragma unroll
            for (int i = 0; i < 16; i++) {
                int flat = i * 256 + tid, cc = flat >> 6, nn = flat & 63;
                ldsT[nn * 65 + cc] = wff[(rt * 64 + cc) * 512 + nt8 * 64 + nn];
            }
            __syncthreads();
#pragma unroll
            for (int i = 0; i < 16; i++) {
                int flat = i * 256 + tid, nn = flat >> 6, cc = flat & 63;
                wfft[(nt8 * 64 + nn) * 512 + rt * 64 + cc] = f2b(ldsT[nn * 65 + cc]);
            }
        }
    } else {                                     // LayerNorm1: one wave per token row
        int row  = (blk - 256) * 4 + (tid >> 6);
        int lane = tid & 63;
        const f32x4 a0 = *(const f32x4*)(x + row * Cdim + lane * 8);
        const f32x4 a1 = *(const f32x4*)(x + row * Cdim + lane * 8 + 4);
        float v[8] = {a0[0], a0[1], a0[2], a0[3], a1[0], a1[1], a1[2], a1[3]};
        float s = 0.f, sq = 0.f;
#pragma unroll
        for (int i = 0; i < 8; i++) { s += v[i]; sq += v[i] * v[i]; }
#pragma unroll
        for (int off = 1; off < 64; off <<= 1) { s += __shfl_xor(s, off); sq += __shfl_xor(sq, off); }
        float mean = s * (1.f / 512.f);
        float var  = sq * (1.f / 512.f) - mean * mean;
        float rstd = rsqrtf(var + 1e-5f);
        const f32x4 g0 = *(const f32x4*)(g + lane * 8);
        const f32x4 g1 = *(const f32x4*)(g + lane * 8 + 4);
        const f32x4 b0 = *(const f32x4*)(b + lane * 8);
        const f32x4 b1 = *(const f32x4*)(b + lane * 8 + 4);
        float gg[8] = {g0[0], g0[1], g0[2], g0[3], g1[0], g1[1], g1[2], g1[3]};
        float bb[8] = {b0[0], b0[1], b0[2], b0[3], b1[0], b1[1], b1[2], b1[3]};
        bf16x8 o;
#pragma unroll
        for (int i = 0; i < 8; i++) o[i] = f2b((v[i] - mean) * rstd * gg[i] + bb[i]);
        *(bf16x8*)(out + row * Cdim + lane * 8) = o;
    }
}

// ---------------- LayerNorm (standalone, for LN2): fp32 in, bf16 out ----------------
__global__ __launch_bounds__(256) void k_ln(const float* __restrict__ x, const float* __restrict__ g,
                                            const float* __restrict__ b, short* __restrict__ out) {
    int row  = blockIdx.x * 4 + (threadIdx.x >> 6);
    int lane = threadIdx.x & 63;
    const f32x4 a0 = *(const f32x4*)(x + row * Cdim + lane * 8);
    const f32x4 a1 = *(const f32x4*)(x + row * Cdim + lane * 8 + 4);
    float v[8] = {a0[0], a0[1], a0[2], a0[3], a1[0], a1[1], a1[2], a1[3]};
    float s = 0.f, sq = 0.f;
#pragma unroll
    for (int i = 0; i < 8; i++) { s += v[i]; sq += v[i] * v[i]; }
#pragma unroll
    for (int off = 1; off < 64; off <<= 1) { s += __shfl_xor(s, off); sq += __shfl_xor(sq, off); }
    float mean = s * (1.f / 512.f);
    float var  = sq * (1.f / 512.f) - mean * mean;
    float rstd = rsqrtf(var + 1e-5f);
    const f32x4 g0 = *(const f32x4*)(g + lane * 8);
    const f32x4 g1 = *(const f32x4*)(g + lane * 8 + 4);
    const f32x4 b0 = *(const f32x4*)(b + lane * 8);
    const f32x4 b1 = *(const f32x4*)(b + lane * 8 + 4);
    float gg[8] = {g0[0], g0[1], g0[2], g0[3], g1[0], g1[1], g1[2], g1[3]};
    float bb[8] = {b0[0], b0[1], b0[2], b0[3], b1[0], b1[1], b1[2], b1[3]};
    bf16x8 o;
#pragma unroll
    for (int i = 0; i < 8; i++) o[i] = f2b((v[i] - mean) * rstd * gg[i] + bb[i]);
    *(bf16x8*)(out + row * Cdim + lane * 8) = o;
}

// ---------------- QKV GEMM v6: 128x64 tile, counted-vmcnt + LDS-transpose vt ----------------
__global__ __launch_bounds__(256) void k_gemm_qkv(const short* __restrict__ A, const short* __restrict__ Wt,
                                                  short* __restrict__ q, short* __restrict__ k,
                                                  short* __restrict__ vt) {
    const int tid = threadIdx.x;
    const int wave = tid >> 6, lane = tid & 63;
    const int quad = lane >> 4, l15 = lane & 15;
    const int m0 = blockIdx.x * 128, n0 = blockIdx.y * 64;
    const int wm = wave & 1, wn = wave >> 1;       // m-half 64, n-half 32
    __shared__ __align__(16) short smem[12288];    // 24KB: As[2][128*32] | Bs[2][64*32]; Tw unions
    short* As = smem;                              // + buf*4096
    short* Bs = smem + 8192;                       // + buf*2048
    f32x4 acc[4][2];
#pragma unroll
    for (int i = 0; i < 4; i++)
#pragma unroll
        for (int j = 0; j < 2; j++) acc[i][j] = (f32x4){0.f, 0.f, 0.f, 0.f};
    const int lr = lane >> 2, lc = lane & 3;       // staging: row = lane/4, 16B-col = lane%4
    const short* Ag = A  + (m0 + wave * 32 + lr) * Cdim + lc * 8;   // 32 A-rows/wave: 2 calls
    const short* Bg = Wt + (n0 + wave * 16 + lr) * Cdim + lc * 8;   // 16 B-rows/wave: 1 call
    // prologue: stage batches 0 and 1 (3 loads each, in order)
    g2l16(Ag,                  As + wave * 1024);
    g2l16(Ag + 16 * Cdim,      As + wave * 1024 + 512);
    g2l16(Bg,                  Bs + wave * 512);
    g2l16(Ag + 32,             As + 4096 + wave * 1024);
    g2l16(Ag + 16 * Cdim + 32, As + 4096 + wave * 1024 + 512);
    g2l16(Bg + 32,             Bs + 2048 + wave * 512);
    for (int kk = 0; kk < 16; kk++) {
        const int cur = kk & 1;
        if (kk < 15) { asm volatile("s_waitcnt vmcnt(3)" ::: "memory"); }   // oldest batch landed
        else         { asm volatile("s_waitcnt vmcnt(0)" ::: "memory"); }
        __builtin_amdgcn_s_barrier();              // buf[cur] ready across all waves
        __builtin_amdgcn_sched_barrier(0);
        bf16x8 a[4], w[2];
#pragma unroll
        for (int mt = 0; mt < 4; mt++) a[mt] = *(const bf16x8*)(As + cur * 4096 + (wm * 64 + mt * 16 + l15) * 32 + quad * 8);
#pragma unroll
        for (int nt = 0; nt < 2; nt++) w[nt] = *(const bf16x8*)(Bs + cur * 2048 + (wn * 32 + nt * 16 + l15) * 32 + quad * 8);
#pragma unroll
        for (int mt = 0; mt < 4; mt++)
#pragma unroll
            for (int nt = 0; nt < 2; nt++)
                acc[mt][nt] = __builtin_amdgcn_mfma_f32_16x16x32_bf16(a[mt], w[nt], acc[mt][nt], 0, 0, 0);
        __builtin_amdgcn_sched_barrier(0);
        __builtin_amdgcn_s_barrier();              // all waves done reading buf[cur]
        if (kk + 2 < 16) {                         // refill the just-freed buffer
            const int k0 = (kk + 2) * 32;
            g2l16(Ag + k0,             As + cur * 4096 + wave * 1024);
            g2l16(Ag + 16 * Cdim + k0, As + cur * 4096 + wave * 1024 + 512);
            g2l16(Bg + k0,             Bs + cur * 2048 + wave * 512);
        }
    }
    // epilogue: n-tile (64) = exactly one head; proj block-uniform
    const int proj = n0 >> 9;
    const int hh   = (n0 & 511) >> 6;
    const int m0w  = m0 + wm * 64;
    if (proj < 2) {                                // q/k: row-major, coalesced enough
#pragma unroll
        for (int mt = 0; mt < 4; mt++) {
#pragma unroll
            for (int r = 0; r < 4; r++) {
                int t  = m0w + mt * 16 + quad * 4 + r;
                int bi = t >> 11, tt = t & 2047;
#pragma unroll
                for (int nt = 0; nt < 2; nt++) {
                    int d = wn * 32 + nt * 16 + l15;
                    short val = f2b(acc[mt][nt][r]);
                    if (proj == 0) q[((bi * Hn + hh) * Tseq + tt) * Dh + d] = val;
                    else           k[((bi * Hn + hh) * Tseq + tt) * Dh + d] = val;
                }
            }
        }
    } else {                                       // vt: transpose through wave-private LDS
        short* Tw = smem + wave * 2176;            // 32 d-rows x 68 stride (post-loop reuse safe)
#pragma unroll
        for (int mt = 0; mt < 4; mt++)
#pragma unroll
            for (int nt = 0; nt < 2; nt++) {
                bf16x4 pk;
#pragma unroll
                for (int r = 0; r < 4; r++) pk[r] = f2b(acc[mt][nt][r]);
                *(bf16x4*)(Tw + (nt * 16 + l15) * 68 + mt * 16 + quad * 4) = pk;
            }
        asm volatile("s_waitcnt lgkmcnt(0)" ::: "memory");   // wave-private: no barrier needed
        const int bi = m0 >> 11, tt0 = m0w & 2047;
        const int g8 = lane >> 3, h8 = lane & 7;   // 8 d-rows per pass, 16B slot within row
        short* vbase = vt + ((size_t)((bi * Hn + hh) * Dh) + wn * 32) * Tseq;
#pragma unroll
        for (int p = 0; p < 4; p++) {
            int dl = p * 8 + g8;
            bf16x8 row = *(const bf16x8*)(Tw + dl * 68 + h8 * 8);
            *(bf16x8*)(vbase + (size_t)dl * Tseq + tt0 + h8 * 8) = row;   // 128B/row coalesced
        }
    }
}

// ---------------- causal flash attention v12d: v12b (setprio REVERTED) + cvt_pk probe ----------------
// Round-19: setprio reverted (m190-style lockstep block: measured -4.4us). cvt_pk P-pack
// added IN ISOLATION to complete R4's attribution: defer-max proven clean (R7); if this
// fails, cvt_pk is the culprit; if it passes, Q-prescale was. Saves ~48 VALU inst/step.
__global__ __launch_bounds__(256, 3) void k_attn(const short* __restrict__ qb, const short* __restrict__ kb,
                                                 const short* __restrict__ vtb, const float* __restrict__ x,
                                                 float* __restrict__ out1) {
    const int wave = threadIdx.x >> 6, lane = threadIdx.x & 63;
    const int quad = lane >> 4, l15 = lane & 15;
    const int D  = blockIdx.y * 32 + blockIdx.x;           // linear dispatch id
    const int j5 = D & 31;
    const int bh = (j5 & 7) * 4 + (j5 >> 3);               // XCD (D&7) -> bh group affinity
    const int u  = D >> 5, kq = u >> 3, d8 = u & 7;
    const int qg = (kq == 0) ? 31 - d8 : (kq == 1) ? 16 + d8 : (kq == 2) ? 15 - d8 : d8;
    const int q0  = qg * 64;                               // block's 64 q-rows
    const int qw0 = q0 + wave * 16;                        // this wave's 16 q-rows
    const int nkt = qg + 1;                                // 64-key tiles (keys <= q0+63)

    const short* Q = qb  + bh * Tseq * Dh;
    const short* K = kb  + bh * Tseq * Dh;
    const short* V = vtb + bh * Dh * Tseq;                 // [d][s]

    __shared__ __align__(16) short Ks[2][64 * 64];         // [key][d], XOR-swizzled cols
    __shared__ __align__(16) short Vs[2][64 * 64];         // [d][s],  XOR-swizzled cols
    __shared__ __align__(16) short Ps[4][16 * 72];         // per-wave P tile [q][s] stride 72
    short* pw = &Ps[wave][0];

    // staging geometry: call covers 8 rows x 128B; lane L -> row lr8, 16B slot lc8^lr8
    const int lr8 = lane >> 3, lc8 = lane & 7;
    const int sw8 = (lc8 ^ lr8) << 3;                      // pre-swizzled source col (shorts)
    const short* Ksrc = K + (wave * 16 + lr8) * Dh + sw8;  // wave stages K rows 16w..16w+15
    const short* Vsrc = V + (wave * 16 + lr8) * Tseq + sw8;// wave stages V d-rows 16w..16w+15

    // prologue: stage tile 0 into buf 0
    g2l16(Ksrc,            &Ks[0][wave * 1024]);
    g2l16(Ksrc + 8 * Dh,   &Ks[0][wave * 1024 + 512]);
    g2l16(Vsrc,            &Vs[0][wave * 1024]);
    g2l16(Vsrc + 8 * Tseq, &Vs[0][wave * 1024 + 512]);

    bf16x8 qa[2];
#pragma unroll
    for (int c = 0; c < 2; c++)
        qa[c] = *(const bf16x8*)(Q + (qw0 + l15) * Dh + c * 32 + quad * 8);

    f32x4 o[4];
#pragma unroll
    for (int i = 0; i < 4; i++) o[i] = (f32x4){0.f, 0.f, 0.f, 0.f};
    float m_i = NEG_BIG, l_i = 0.f;                        // per-lane: q-row = qw0 + l15

    const float sc = 0.125f * 1.44269504089f;              // scale * log2(e)
    const int sx = l15 & 7;                                // read-side swizzle (row&7)

    __syncthreads();                                       // tile 0 staged (drains vmcnt)

    for (int kt = 0; kt < nkt; kt++) {
        const short* Kb = &Ks[kt & 1][0];
        const short* Vb = &Vs[kt & 1][0];
        if (kt + 1 < nkt) {                                // stage next tile into other buf
            g2l16(Ksrc + (kt + 1) * 64 * Dh,            &Ks[(kt + 1) & 1][wave * 1024]);
            g2l16(Ksrc + (kt + 1) * 64 * Dh + 8 * Dh,   &Ks[(kt + 1) & 1][wave * 1024 + 512]);
            g2l16(Vsrc + (kt + 1) * 64,                 &Vs[(kt + 1) & 1][wave * 1024]);
            g2l16(Vsrc + (kt + 1) * 64 + 8 * Tseq,      &Vs[(kt + 1) & 1][wave * 1024 + 512]);
        }
        const int s0 = kt * 64;
        // ---- QK^T from LDS (swizzled reads) ----
        f32x4 st[4];
#pragma unroll
        for (int nt = 0; nt < 4; nt++) {
            bf16x8 k0 = *(const bf16x8*)(Kb + (nt * 16 + l15) * 64 + ((quad ^ sx) << 3));
            bf16x8 k1 = *(const bf16x8*)(Kb + (nt * 16 + l15) * 64 + (((4 | quad) ^ sx) << 3));
            f32x4 z = (f32x4){0.f, 0.f, 0.f, 0.f};
            z = __builtin_amdgcn_mfma_f32_16x16x32_bf16(k0, qa[0], z, 0, 0, 0);
            z = __builtin_amdgcn_mfma_f32_16x16x32_bf16(k1, qa[1], z, 0, 0, 0);
            st[nt] = z;
        }
        // ---- mask + scale (only the last tile crosses the diagonal for every wave) ----
        const int qq = qw0 + l15;
        if (kt == nkt - 1) {
#pragma unroll
            for (int nt = 0; nt < 4; nt++)
#pragma unroll
                for (int r = 0; r < 4; r++) {
                    int s = s0 + nt * 16 + quad * 4 + r;
                    st[nt][r] = (s > qq) ? NEG_BIG : st[nt][r] * sc;
                }
        } else {
#pragma unroll
            for (int nt = 0; nt < 4; nt++)
#pragma unroll
                for (int r = 0; r < 4; r++) st[nt][r] *= sc;
        }
        // ---- online softmax with defer-max (THR=8, wave-uniform skip) ----
        float mx = fmaxf(fmaxf(fmaxf(st[0][0], st[0][1]), fmaxf(st[0][2], st[0][3])),
                         fmaxf(fmaxf(st[1][0], st[1][1]), fmaxf(st[1][2], st[1][3])));
        mx = fmaxf(mx, fmaxf(fmaxf(fmaxf(st[2][0], st[2][1]), fmaxf(st[2][2], st[2][3])),
                             fmaxf(fmaxf(st[3][0], st[3][1]), fmaxf(st[3][2], st[3][3]))));
        mx = fmaxf(mx, __shfl_xor(mx, 16));
        mx = fmaxf(mx, __shfl_xor(mx, 32));
        if (!__all(mx <= m_i + 8.f)) {             // rescale only on significant max growth
            float mn    = fmaxf(m_i, mx);
            float alpha = __builtin_amdgcn_exp2f(m_i - mn);
            m_i = mn;
            l_i *= alpha;
#pragma unroll
            for (int r = 0; r < 4; r++) {
                float ar = __shfl(alpha, quad * 4 + r);
#pragma unroll
                for (int dt = 0; dt < 4; dt++) o[dt][r] *= ar;
            }
        }
        float rs = 0.f;
#pragma unroll
        for (int nt = 0; nt < 4; nt++) {
            float p0 = __builtin_amdgcn_exp2f(st[nt][0] - m_i);    // masked -> 0; bounded 2^8
            float p1 = __builtin_amdgcn_exp2f(st[nt][1] - m_i);
            float p2 = __builtin_amdgcn_exp2f(st[nt][2] - m_i);
            float p3 = __builtin_amdgcn_exp2f(st[nt][3] - m_i);
            rs += (p0 + p1) + (p2 + p3);
            unsigned lo, hi;                       // pack 4 vals in 2 inst (vs 4x int-RNE f2b)
            asm("v_cvt_pk_bf16_f32 %0, %1, %2" : "=v"(lo) : "v"(p0), "v"(p1));
            asm("v_cvt_pk_bf16_f32 %0, %1, %2" : "=v"(hi) : "v"(p2), "v"(p3));
            uint2 pk2 = {lo, hi};
            *(uint2*)(pw + l15 * 72 + nt * 16 + quad * 4) = pk2;
        }
        rs += __shfl_xor(rs, 16);
        rs += __shfl_xor(rs, 32);
        l_i += rs;
        asm volatile("s_waitcnt lgkmcnt(0)" ::: "memory");
        bf16x8 pa[2];
#pragma unroll
        for (int c = 0; c < 2; c++)
            pa[c] = *(const bf16x8*)(pw + l15 * 72 + c * 32 + quad * 8);
        // ---- PV from LDS V (swizzled reads) ----
#pragma unroll
        for (int c = 0; c < 2; c++)
#pragma unroll
            for (int v4 = 0; v4 < 4; v4++) {
                bf16x8 vb = *(const bf16x8*)(Vb + (v4 * 16 + l15) * 64 + ((((c << 2) | quad) ^ sx) << 3));
                o[v4] = __builtin_amdgcn_mfma_f32_16x16x32_bf16(pa[c], vb, o[v4], 0, 0, 0);
            }
        __syncthreads();    // waves done reading buf[kt&1]; staged tile kt+1 complete (vmcnt)
    }
    // ---- per-wave epilogue: rows qw0..qw0+15, no cross-wave combine ----
    const int bi = bh >> 3, hh = bh & 7;
#pragma unroll
    for (int r = 0; r < 4; r++) {
        int row = quad * 4 + r;
        float Lr  = __shfl(l_i, row);              // l_i uniform across the 4 quads per l15
        float inv = 1.f / Lr;
#pragma unroll
        for (int v4 = 0; v4 < 4; v4++) {
            int t   = qw0 + row;
            int idx = (bi * Tseq + t) * Cdim + hh * Dh + v4 * 16 + l15;
            out1[idx] = x[idx] + o[v4][r] * inv;
        }
    }
}

// ---------------- FF GEMM v5: 64x64 tile, counted-vmcnt pipeline ----------------
__global__ __launch_bounds__(256) void k_gemm_ff(const short* __restrict__ A, const short* __restrict__ Wt,
                                                 const float* __restrict__ bias, const float* __restrict__ res,
                                                 float* __restrict__ out) {
    const int tid = threadIdx.x;
    const int wave = tid >> 6, lane = tid & 63;
    const int quad = lane >> 4, l15 = lane & 15;
    const int m0 = blockIdx.x * 64, n0 = blockIdx.y * 64;
    const int wm = wave & 1, wn = wave >> 1;           // wave -> 32-row half, 32-col half
    __shared__ __align__(16) short As[2][64 * 32];     // 4 KB per buf
    __shared__ __align__(16) short Bs[2][64 * 32];
    f32x4 acc[2][2];
#pragma unroll
    for (int i = 0; i < 2; i++)
#pragma unroll
        for (int j = 0; j < 2; j++) acc[i][j] = (f32x4){0.f, 0.f, 0.f, 0.f};
    const int lr = lane >> 2, lc = lane & 3;           // 16 rows x 4 slots per g2l16 call
    const short* Ag = A  + (m0 + wave * 16 + lr) * Cdim + lc * 8;   // 16 A-rows/wave: 1 call
    const short* Bg = Wt + (n0 + wave * 16 + lr) * Cdim + lc * 8;   // 16 B-rows/wave: 1 call
    // prologue: stage batches 0 and 1 (2 loads each, in order)
    g2l16(Ag,       &As[0][wave * 512]);
    g2l16(Bg,       &Bs[0][wave * 512]);
    g2l16(Ag + 32,  &As[1][wave * 512]);
    g2l16(Bg + 32,  &Bs[1][wave * 512]);
    for (int kk = 0; kk < 16; kk++) {
        const int cur = kk & 1;
        if (kk < 15) { asm volatile("s_waitcnt vmcnt(2)" ::: "memory"); }   // oldest batch landed
        else         { asm volatile("s_waitcnt vmcnt(0)" ::: "memory"); }
        __builtin_amdgcn_s_barrier();              // buf[cur] ready across all waves
        __builtin_amdgcn_sched_barrier(0);
        bf16x8 a[2], w[2];
#pragma unroll
        for (int mt = 0; mt < 2; mt++) a[mt] = *(const bf16x8*)(&As[cur][(wm * 32 + mt * 16 + l15) * 32 + quad * 8]);
#pragma unroll
        for (int nt = 0; nt < 2; nt++) w[nt] = *(const bf16x8*)(&Bs[cur][(wn * 32 + nt * 16 + l15) * 32 + quad * 8]);
#pragma unroll
        for (int mt = 0; mt < 2; mt++)
#pragma unroll
            for (int nt = 0; nt < 2; nt++)
                acc[mt][nt] = __builtin_amdgcn_mfma_f32_16x16x32_bf16(a[mt], w[nt], acc[mt][nt], 0, 0, 0);
        __builtin_amdgcn_sched_barrier(0);
        __builtin_amdgcn_s_barrier();              // all waves done reading buf[cur]
        if (kk + 2 < 16) {                         // refill the just-freed buffer
            const int k0 = (kk + 2) * 32;
            g2l16(Ag + k0, &As[cur][wave * 512]);
            g2l16(Bg + k0, &Bs[cur][wave * 512]);
        }
    }
    const int m0w = m0 + wm * 32, n0w = n0 + wn * 32;
#pragma unroll
    for (int mt = 0; mt < 2; mt++) {
#pragma unroll
        for (int r = 0; r < 4; r++) {
            int t = m0w + mt * 16 + quad * 4 + r;
#pragma unroll
            for (int nt = 0; nt < 2; nt++) {
                int n = n0w + nt * 16 + l15;
                float fv = acc[mt][nt][r] + bias[n];
                fv = fmaxf(fv, 0.f);
                out[t * Cdim + n] = res[t * Cdim + n] + fv;
            }
        }
    }
}

extern "C" void kernel_launch(void* const* d_in, const int* in_sizes, int n_in,
                              void* d_out, int out_size, void* d_ws, size_t ws_size,
                              hipStream_t stream) {
    const float* x   = (const float*)d_in[0];
    const float* wq  = (const float*)d_in[1];
    const float* wk  = (const float*)d_in[2];
    const float* wv  = (const float*)d_in[3];
    const float* wff = (const float*)d_in[4];
    const float* bff = (const float*)d_in[5];
    const float* g1  = (const float*)d_in[6];
    const float* b1  = (const float*)d_in[7];
    const float* g2  = (const float*)d_in[8];
    const float* b2  = (const float*)d_in[9];

    char* p = (char*)d_ws;                                  // ~50 MB total scratch
    short* wqkvt = (short*)p; p += (size_t)NQKV * Cdim * 2;
    short* wfft  = (short*)p; p += (size_t)Cdim * Cdim * 2;
    short* h1    = (short*)p; p += (size_t)BT * Cdim * 2;   // reused as h2 after attention
    short* qb    = (short*)p; p += (size_t)BT * Cdim * 2;
    short* kb    = (short*)p; p += (size_t)BT * Cdim * 2;
    short* vtb   = (short*)p; p += (size_t)BT * Cdim * 2;
    float* out1  = (float*)p; p += (size_t)BT * Cdim * 4;

    hipLaunchKernelGGL(k_prep,     dim3(2304),    dim3(256), 0, stream,
                       wq, wk, wv, wff, wqkvt, wfft, x, g1, b1, h1);
    hipLaunchKernelGGL(k_gemm_qkv, dim3(64, 24),  dim3(256), 0, stream, h1, wqkvt, qb, kb, vtb);
    hipLaunchKernelGGL(k_attn,     dim3(32, 32),  dim3(256), 0, stream, qb, kb, vtb, x, out1);
    hipLaunchKernelGGL(k_ln,       dim3(2048),    dim3(256), 0, stream, out1, g2, b2, h1);
    hipLaunchKernelGGL(k_gemm_ff,  dim3(128, 8),  dim3(256), 0, stream, h1, wfft, bff, out1, (float*)d_out);
}

// Round 10
// 164.390 us; speedup vs baseline: 1.0303x; 1.0049x over previous
//
#include <hip/hip_runtime.h>

#define Bsz  4
#define Tseq 2048
#define Cdim 512
#define Hn   8
#define Dh   64
#define BT   8192     // Bsz*Tseq tokens
#define NQKV 1536
#define NEG_BIG (-1e30f)

typedef __attribute__((ext_vector_type(8))) short bf16x8;  // 8 bf16 = 4 VGPRs
typedef __attribute__((ext_vector_type(4))) short bf16x4;  // 4 bf16 = 2 VGPRs
typedef __attribute__((ext_vector_type(4))) float f32x4;

__device__ __forceinline__ float b2f(short s) {
    unsigned u = ((unsigned)(unsigned short)s) << 16;
    float f; __builtin_memcpy(&f, &u, 4); return f;
}
__device__ __forceinline__ short f2b(float f) {
    unsigned u; __builtin_memcpy(&u, &f, 4);
    u = (u + 0x7fffu + ((u >> 16) & 1u)) >> 16;   // RNE
    return (short)u;
}
// async global->LDS, 16B/lane; LDS dest = wave-uniform base + lane*16
__device__ __forceinline__ void g2l16(const short* g, short* l) {
    __builtin_amdgcn_global_load_lds(
        (const __attribute__((address_space(1))) unsigned int*)(uintptr_t)g,
        (__attribute__((address_space(3))) unsigned int*)l, 16, 0, 0);
}

// ---------------- prep: fused weight transpose (blocks 0..255) + LayerNorm1 (blocks 256..2303) ----------------
__global__ __launch_bounds__(256) void k_prep(const float* __restrict__ wq, const float* __restrict__ wk,
                                              const float* __restrict__ wv, const float* __restrict__ wff,
                                              short* __restrict__ wqkvt, short* __restrict__ wfft,
                                              const float* __restrict__ x, const float* __restrict__ g,
                                              const float* __restrict__ b, short* __restrict__ out) {
    const int blk = blockIdx.x, tid = threadIdx.x;
    if (blk < 256) {
        __shared__ float ldsT[64 * 65];          // 64x64 tile, pad 65: conflict-free both phases
        if (blk < 192) {                         // QKV heads: per-head 512x64 -> 64x512
            int hm = blk >> 3, ct = blk & 7;
            int proj = hm >> 3, h = hm & 7;
            const float* w = (proj == 0) ? wq : (proj == 1 ? wk : wv);
#pragma unroll
            for (int i = 0; i < 16; i++) {
                int flat = i * 256 + tid, cc = flat >> 6, dd = flat & 63;
                ldsT[dd * 65 + cc] = w[(h * 512 + ct * 64 + cc) * 64 + dd];   // coalesced in dd
            }
            __syncthreads();
#pragma unroll
            for (int i = 0; i < 16; i++) {
                int flat = i * 256 + tid, dd = flat >> 6, cc = flat & 63;
                int n = proj * 512 + h * 64 + dd;
                wqkvt[n * 512 + ct * 64 + cc] = f2b(ldsT[dd * 65 + cc]);      // coalesced in cc
            }
        } else {                                 // FF: 512x512 -> 512x512 transposed
            int b2 = blk - 192, rt = b2 >> 3, nt8 = b2 & 7;
#pragma unroll
            for (int i = 0; i < 16; i++) {
                int flat = i * 256 + tid, cc = flat >> 6, nn = flat & 63;
                ldsT[nn * 65 + cc] = wff[(rt * 64 + cc) * 512 + nt8 * 64 + nn];
            }
            __syncthreads();
#pragma unroll
            for (int i = 0; i < 16; i++) {
                int flat = i * 256 + tid, nn = flat >> 6, cc = flat & 63;
                wfft[(nt8 * 64 + nn) * 512 + rt * 64 + cc] = f2b(ldsT[nn * 65 + cc]);
            }
        }
    } else {                                     // LayerNorm1: one wave per token row
        int row  = (blk - 256) * 4 + (tid >> 6);
        int lane = tid & 63;
        const f32x4 a0 = *(const f32x4*)(x + row * Cdim + lane * 8);
        const f32x4 a1 = *(const f32x4*)(x + row * Cdim + lane * 8 + 4);
        float v[8] = {a0[0], a0[1], a0[2], a0[3], a1[0], a1[1], a1[2], a1[3]};
        float s = 0.f, sq = 0.f;
#pragma unroll
        for (int i = 0; i < 8; i++) { s += v[i]; sq += v[i] * v[i]; }
#pragma unroll
        for (int off = 1; off < 64; off <<= 1) { s += __shfl_xor(s, off); sq += __shfl_xor(sq, off); }
        float mean = s * (1.f / 512.f);
        float var  = sq * (1.f / 512.f) - mean * mean;
        float rstd = rsqrtf(var + 1e-5f);
        const f32x4 g0 = *(const f32x4*)(g + lane * 8);
        const f32x4 g1 = *(const f32x4*)(g + lane * 8 + 4);
        const f32x4 b0 = *(const f32x4*)(b + lane * 8);
        const f32x4 b1 = *(const f32x4*)(b + lane * 8 + 4);
        float gg[8] = {g0[0], g0[1], g0[2], g0[3], g1[0], g1[1], g1[2], g1[3]};
        float bb[8] = {b0[0], b0[1], b0[2], b0[3], b1[0], b1[1], b1[2], b1[3]};
        bf16x8 o;
#pragma unroll
        for (int i = 0; i < 8; i++) o[i] = f2b((v[i] - mean) * rstd * gg[i] + bb[i]);
        *(bf16x8*)(out + row * Cdim + lane * 8) = o;
    }
}

// ---------------- LayerNorm (standalone, for LN2): fp32 in, bf16 out ----------------
__global__ __launch_bounds__(256) void k_ln(const float* __restrict__ x, const float* __restrict__ g,
                                            const float* __restrict__ b, short* __restrict__ out) {
    int row  = blockIdx.x * 4 + (threadIdx.x >> 6);
    int lane = threadIdx.x & 63;
    const f32x4 a0 = *(const f32x4*)(x + row * Cdim + lane * 8);
    const f32x4 a1 = *(const f32x4*)(x + row * Cdim + lane * 8 + 4);
    float v[8] = {a0[0], a0[1], a0[2], a0[3], a1[0], a1[1], a1[2], a1[3]};
    float s = 0.f, sq = 0.f;
#pragma unroll
    for (int i = 0; i < 8; i++) { s += v[i]; sq += v[i] * v[i]; }
#pragma unroll
    for (int off = 1; off < 64; off <<= 1) { s += __shfl_xor(s, off); sq += __shfl_xor(sq, off); }
    float mean = s * (1.f / 512.f);
    float var  = sq * (1.f / 512.f) - mean * mean;
    float rstd = rsqrtf(var + 1e-5f);
    const f32x4 g0 = *(const f32x4*)(g + lane * 8);
    const f32x4 g1 = *(const f32x4*)(g + lane * 8 + 4);
    const f32x4 b0 = *(const f32x4*)(b + lane * 8);
    const f32x4 b1 = *(const f32x4*)(b + lane * 8 + 4);
    float gg[8] = {g0[0], g0[1], g0[2], g0[3], g1[0], g1[1], g1[2], g1[3]};
    float bb[8] = {b0[0], b0[1], b0[2], b0[3], b1[0], b1[1], b1[2], b1[3]};
    bf16x8 o;
#pragma unroll
    for (int i = 0; i < 8; i++) o[i] = f2b((v[i] - mean) * rstd * gg[i] + bb[i]);
    *(bf16x8*)(out + row * Cdim + lane * 8) = o;
}

// ---------------- QKV GEMM v6: 128x64 tile, counted-vmcnt + LDS-transpose vt ----------------
__global__ __launch_bounds__(256) void k_gemm_qkv(const short* __restrict__ A, const short* __restrict__ Wt,
                                                  short* __restrict__ q, short* __restrict__ k,
                                                  short* __restrict__ vt) {
    const int tid = threadIdx.x;
    const int wave = tid >> 6, lane = tid & 63;
    const int quad = lane >> 4, l15 = lane & 15;
    const int m0 = blockIdx.x * 128, n0 = blockIdx.y * 64;
    const int wm = wave & 1, wn = wave >> 1;       // m-half 64, n-half 32
    __shared__ __align__(16) short smem[12288];    // 24KB: As[2][128*32] | Bs[2][64*32]; Tw unions
    short* As = smem;                              // + buf*4096
    short* Bs = smem + 8192;                       // + buf*2048
    f32x4 acc[4][2];
#pragma unroll
    for (int i = 0; i < 4; i++)
#pragma unroll
        for (int j = 0; j < 2; j++) acc[i][j] = (f32x4){0.f, 0.f, 0.f, 0.f};
    const int lr = lane >> 2, lc = lane & 3;       // staging: row = lane/4, 16B-col = lane%4
    const short* Ag = A  + (m0 + wave * 32 + lr) * Cdim + lc * 8;   // 32 A-rows/wave: 2 calls
    const short* Bg = Wt + (n0 + wave * 16 + lr) * Cdim + lc * 8;   // 16 B-rows/wave: 1 call
    // prologue: stage batches 0 and 1 (3 loads each, in order)
    g2l16(Ag,                  As + wave * 1024);
    g2l16(Ag + 16 * Cdim,      As + wave * 1024 + 512);
    g2l16(Bg,                  Bs + wave * 512);
    g2l16(Ag + 32,             As + 4096 + wave * 1024);
    g2l16(Ag + 16 * Cdim + 32, As + 4096 + wave * 1024 + 512);
    g2l16(Bg + 32,             Bs + 2048 + wave * 512);
    for (int kk = 0; kk < 16; kk++) {
        const int cur = kk & 1;
        if (kk < 15) { asm volatile("s_waitcnt vmcnt(3)" ::: "memory"); }   // oldest batch landed
        else         { asm volatile("s_waitcnt vmcnt(0)" ::: "memory"); }
        __builtin_amdgcn_s_barrier();              // buf[cur] ready across all waves
        __builtin_amdgcn_sched_barrier(0);
        bf16x8 a[4], w[2];
#pragma unroll
        for (int mt = 0; mt < 4; mt++) a[mt] = *(const bf16x8*)(As + cur * 4096 + (wm * 64 + mt * 16 + l15) * 32 + quad * 8);
#pragma unroll
        for (int nt = 0; nt < 2; nt++) w[nt] = *(const bf16x8*)(Bs + cur * 2048 + (wn * 32 + nt * 16 + l15) * 32 + quad * 8);
#pragma unroll
        for (int mt = 0; mt < 4; mt++)
#pragma unroll
            for (int nt = 0; nt < 2; nt++)
                acc[mt][nt] = __builtin_amdgcn_mfma_f32_16x16x32_bf16(a[mt], w[nt], acc[mt][nt], 0, 0, 0);
        __builtin_amdgcn_sched_barrier(0);
        __builtin_amdgcn_s_barrier();              // all waves done reading buf[cur]
        if (kk + 2 < 16) {                         // refill the just-freed buffer
            const int k0 = (kk + 2) * 32;
            g2l16(Ag + k0,             As + cur * 4096 + wave * 1024);
            g2l16(Ag + 16 * Cdim + k0, As + cur * 4096 + wave * 1024 + 512);
            g2l16(Bg + k0,             Bs + cur * 2048 + wave * 512);
        }
    }
    // epilogue: n-tile (64) = exactly one head; proj block-uniform
    const int proj = n0 >> 9;
    const int hh   = (n0 & 511) >> 6;
    const int m0w  = m0 + wm * 64;
    if (proj < 2) {                                // q/k: row-major, coalesced enough
#pragma unroll
        for (int mt = 0; mt < 4; mt++) {
#pragma unroll
            for (int r = 0; r < 4; r++) {
                int t  = m0w + mt * 16 + quad * 4 + r;
                int bi = t >> 11, tt = t & 2047;
#pragma unroll
                for (int nt = 0; nt < 2; nt++) {
                    int d = wn * 32 + nt * 16 + l15;
                    short val = f2b(acc[mt][nt][r]);
                    if (proj == 0) q[((bi * Hn + hh) * Tseq + tt) * Dh + d] = val;
                    else           k[((bi * Hn + hh) * Tseq + tt) * Dh + d] = val;
                }
            }
        }
    } else {                                       // vt: transpose through wave-private LDS
        short* Tw = smem + wave * 2176;            // 32 d-rows x 68 stride (post-loop reuse safe)
#pragma unroll
        for (int mt = 0; mt < 4; mt++)
#pragma unroll
            for (int nt = 0; nt < 2; nt++) {
                bf16x4 pk;
#pragma unroll
                for (int r = 0; r < 4; r++) pk[r] = f2b(acc[mt][nt][r]);
                *(bf16x4*)(Tw + (nt * 16 + l15) * 68 + mt * 16 + quad * 4) = pk;
            }
        asm volatile("s_waitcnt lgkmcnt(0)" ::: "memory");   // wave-private: no barrier needed
        const int bi = m0 >> 11, tt0 = m0w & 2047;
        const int g8 = lane >> 3, h8 = lane & 7;   // 8 d-rows per pass, 16B slot within row
        short* vbase = vt + ((size_t)((bi * Hn + hh) * Dh) + wn * 32) * Tseq;
#pragma unroll
        for (int p = 0; p < 4; p++) {
            int dl = p * 8 + g8;
            bf16x8 row = *(const bf16x8*)(Tw + dl * 68 + h8 * 8);
            *(bf16x8*)(vbase + (size_t)dl * Tseq + tt0 + h8 * 8) = row;   // 128B/row coalesced
        }
    }
}

// ---------------- causal flash attention v12e: v12d + XOR-swizzled P buffer (LDS 41984->40960) ----------------
// Round-20: LDS was the residency cap (41984B -> 3 blocks/CU). P tile's stride-72 pad
// replaced by 16B-slot XOR swizzle (same trick as Ks/Vs): Ps = 4x16x64 shorts = 8KB exactly,
// total 40960B -> 4 blocks/CU (+33% residency). Mapping verified: writer slot 2nt+(quad>>1)
// == reader slot 4c+quad for matching elements; 2-way bank aliasing = free (m136).
__global__ __launch_bounds__(256, 3) void k_attn(const short* __restrict__ qb, const short* __restrict__ kb,
                                                 const short* __restrict__ vtb, const float* __restrict__ x,
                                                 float* __restrict__ out1) {
    const int wave = threadIdx.x >> 6, lane = threadIdx.x & 63;
    const int quad = lane >> 4, l15 = lane & 15;
    const int D  = blockIdx.y * 32 + blockIdx.x;           // linear dispatch id
    const int j5 = D & 31;
    const int bh = (j5 & 7) * 4 + (j5 >> 3);               // XCD (D&7) -> bh group affinity
    const int u  = D >> 5, kq = u >> 3, d8 = u & 7;
    const int qg = (kq == 0) ? 31 - d8 : (kq == 1) ? 16 + d8 : (kq == 2) ? 15 - d8 : d8;
    const int q0  = qg * 64;                               // block's 64 q-rows
    const int qw0 = q0 + wave * 16;                        // this wave's 16 q-rows
    const int nkt = qg + 1;                                // 64-key tiles (keys <= q0+63)

    const short* Q = qb  + bh * Tseq * Dh;
    const short* K = kb  + bh * Tseq * Dh;
    const short* V = vtb + bh * Dh * Tseq;                 // [d][s]

    __shared__ __align__(16) short Ks[2][64 * 64];         // [key][d], XOR-swizzled cols
    __shared__ __align__(16) short Vs[2][64 * 64];         // [d][s],  XOR-swizzled cols
    __shared__ __align__(16) short Ps[4][16 * 64];         // per-wave P tile, XOR-swizzled slots
    short* pw = &Ps[wave][0];

    // staging geometry: call covers 8 rows x 128B; lane L -> row lr8, 16B slot lc8^lr8
    const int lr8 = lane >> 3, lc8 = lane & 7;
    const int sw8 = (lc8 ^ lr8) << 3;                      // pre-swizzled source col (shorts)
    const short* Ksrc = K + (wave * 16 + lr8) * Dh + sw8;  // wave stages K rows 16w..16w+15
    const short* Vsrc = V + (wave * 16 + lr8) * Tseq + sw8;// wave stages V d-rows 16w..16w+15

    // prologue: stage tile 0 into buf 0
    g2l16(Ksrc,            &Ks[0][wave * 1024]);
    g2l16(Ksrc + 8 * Dh,   &Ks[0][wave * 1024 + 512]);
    g2l16(Vsrc,            &Vs[0][wave * 1024]);
    g2l16(Vsrc + 8 * Tseq, &Vs[0][wave * 1024 + 512]);

    bf16x8 qa[2];
#pragma unroll
    for (int c = 0; c < 2; c++)
        qa[c] = *(const bf16x8*)(Q + (qw0 + l15) * Dh + c * 32 + quad * 8);

    f32x4 o[4];
#pragma unroll
    for (int i = 0; i < 4; i++) o[i] = (f32x4){0.f, 0.f, 0.f, 0.f};
    float m_i = NEG_BIG, l_i = 0.f;                        // per-lane: q-row = qw0 + l15

    const float sc = 0.125f * 1.44269504089f;              // scale * log2(e)
    const int sx = l15 & 7;                                // read-side swizzle (row&7)

    __syncthreads();                                       // tile 0 staged (drains vmcnt)

    for (int kt = 0; kt < nkt; kt++) {
        const short* Kb = &Ks[kt & 1][0];
        const short* Vb = &Vs[kt & 1][0];
        if (kt + 1 < nkt) {                                // stage next tile into other buf
            g2l16(Ksrc + (kt + 1) * 64 * Dh,            &Ks[(kt + 1) & 1][wave * 1024]);
            g2l16(Ksrc + (kt + 1) * 64 * Dh + 8 * Dh,   &Ks[(kt + 1) & 1][wave * 1024 + 512]);
            g2l16(Vsrc + (kt + 1) * 64,                 &Vs[(kt + 1) & 1][wave * 1024]);
            g2l16(Vsrc + (kt + 1) * 64 + 8 * Tseq,      &Vs[(kt + 1) & 1][wave * 1024 + 512]);
        }
        const int s0 = kt * 64;
        // ---- QK^T from LDS (swizzled reads) ----
        f32x4 st[4];
#pragma unroll
        for (int nt = 0; nt < 4; nt++) {
            bf16x8 k0 = *(const bf16x8*)(Kb + (nt * 16 + l15) * 64 + ((quad ^ sx) << 3));
            bf16x8 k1 = *(const bf16x8*)(Kb + (nt * 16 + l15) * 64 + (((4 | quad) ^ sx) << 3));
            f32x4 z = (f32x4){0.f, 0.f, 0.f, 0.f};
            z = __builtin_amdgcn_mfma_f32_16x16x32_bf16(k0, qa[0], z, 0, 0, 0);
            z = __builtin_amdgcn_mfma_f32_16x16x32_bf16(k1, qa[1], z, 0, 0, 0);
            st[nt] = z;
        }
        // ---- mask + scale (only the last tile crosses the diagonal for every wave) ----
        const int qq = qw0 + l15;
        if (kt == nkt - 1) {
#pragma unroll
            for (int nt = 0; nt < 4; nt++)
#pragma unroll
                for (int r = 0; r < 4; r++) {
                    int s = s0 + nt * 16 + quad * 4 + r;
                    st[nt][r] = (s > qq) ? NEG_BIG : st[nt][r] * sc;
                }
        } else {
#pragma unroll
            for (int nt = 0; nt < 4; nt++)
#pragma unroll
                for (int r = 0; r < 4; r++) st[nt][r] *= sc;
        }
        // ---- online softmax with defer-max (THR=8, wave-uniform skip) ----
        float mx = fmaxf(fmaxf(fmaxf(st[0][0], st[0][1]), fmaxf(st[0][2], st[0][3])),
                         fmaxf(fmaxf(st[1][0], st[1][1]), fmaxf(st[1][2], st[1][3])));
        mx = fmaxf(mx, fmaxf(fmaxf(fmaxf(st[2][0], st[2][1]), fmaxf(st[2][2], st[2][3])),
                             fmaxf(fmaxf(st[3][0], st[3][1]), fmaxf(st[3][2], st[3][3]))));
        mx = fmaxf(mx, __shfl_xor(mx, 16));
        mx = fmaxf(mx, __shfl_xor(mx, 32));
        if (!__all(mx <= m_i + 8.f)) {             // rescale only on significant max growth
            float mn    = fmaxf(m_i, mx);
            float alpha = __builtin_amdgcn_exp2f(m_i - mn);
            m_i = mn;
            l_i *= alpha;
#pragma unroll
            for (int r = 0; r < 4; r++) {
                float ar = __shfl(alpha, quad * 4 + r);
#pragma unroll
                for (int dt = 0; dt < 4; dt++) o[dt][r] *= ar;
            }
        }
        float rs = 0.f;
#pragma unroll
        for (int nt = 0; nt < 4; nt++) {
            float p0 = __builtin_amdgcn_exp2f(st[nt][0] - m_i);    // masked -> 0; bounded 2^8
            float p1 = __builtin_amdgcn_exp2f(st[nt][1] - m_i);
            float p2 = __builtin_amdgcn_exp2f(st[nt][2] - m_i);
            float p3 = __builtin_amdgcn_exp2f(st[nt][3] - m_i);
            rs += (p0 + p1) + (p2 + p3);
            unsigned lo, hi;                       // pack 4 vals in 2 inst (vs 4x int-RNE f2b)
            asm("v_cvt_pk_bf16_f32 %0, %1, %2" : "=v"(lo) : "v"(p0), "v"(p1));
            asm("v_cvt_pk_bf16_f32 %0, %1, %2" : "=v"(hi) : "v"(p2), "v"(p3));
            uint2 pk2 = {lo, hi};
            // swizzled P write: 16B slot s = 2nt+(quad>>1), half h = quad&1; slot ^= sx
            *(uint2*)(pw + l15 * 64 + (((2 * nt + (quad >> 1)) ^ sx) << 3) + (quad & 1) * 4) = pk2;
        }
        rs += __shfl_xor(rs, 16);
        rs += __shfl_xor(rs, 32);
        l_i += rs;
        asm volatile("s_waitcnt lgkmcnt(0)" ::: "memory");
        bf16x8 pa[2];
#pragma unroll
        for (int c = 0; c < 2; c++)                        // swizzled P read: slot 4c+quad ^ sx
            pa[c] = *(const bf16x8*)(pw + l15 * 64 + (((c * 4 + quad) ^ sx) << 3));
        // ---- PV from LDS V (swizzled reads) ----
#pragma unroll
        for (int c = 0; c < 2; c++)
#pragma unroll
            for (int v4 = 0; v4 < 4; v4++) {
                bf16x8 vb = *(const bf16x8*)(Vb + (v4 * 16 + l15) * 64 + ((((c << 2) | quad) ^ sx) << 3));
                o[v4] = __builtin_amdgcn_mfma_f32_16x16x32_bf16(pa[c], vb, o[v4], 0, 0, 0);
            }
        __syncthreads();    // waves done reading buf[kt&1]; staged tile kt+1 complete (vmcnt)
    }
    // ---- per-wave epilogue: rows qw0..qw0+15, no cross-wave combine ----
    const int bi = bh >> 3, hh = bh & 7;
#pragma unroll
    for (int r = 0; r < 4; r++) {
        int row = quad * 4 + r;
        float Lr  = __shfl(l_i, row);              // l_i uniform across the 4 quads per l15
        float inv = 1.f / Lr;
#pragma unroll
        for (int v4 = 0; v4 < 4; v4++) {
            int t   = qw0 + row;
            int idx = (bi * Tseq + t) * Cdim + hh * Dh + v4 * 16 + l15;
            out1[idx] = x[idx] + o[v4][r] * inv;
        }
    }
}

// ---------------- FF GEMM v5: 64x64 tile, counted-vmcnt pipeline ----------------
__global__ __launch_bounds__(256) void k_gemm_ff(const short* __restrict__ A, const short* __restrict__ Wt,
                                                 const float* __restrict__ bias, const float* __restrict__ res,
                                                 float* __restrict__ out) {
    const int tid = threadIdx.x;
    const int wave = tid >> 6, lane = tid & 63;
    const int quad = lane >> 4, l15 = lane & 15;
    const int m0 = blockIdx.x * 64, n0 = blockIdx.y * 64;
    const int wm = wave & 1, wn = wave >> 1;           // wave -> 32-row half, 32-col half
    __shared__ __align__(16) short As[2][64 * 32];     // 4 KB per buf
    __shared__ __align__(16) short Bs[2][64 * 32];
    f32x4 acc[2][2];
#pragma unroll
    for (int i = 0; i < 2; i++)
#pragma unroll
        for (int j = 0; j < 2; j++) acc[i][j] = (f32x4){0.f, 0.f, 0.f, 0.f};
    const int lr = lane >> 2, lc = lane & 3;           // 16 rows x 4 slots per g2l16 call
    const short* Ag = A  + (m0 + wave * 16 + lr) * Cdim + lc * 8;   // 16 A-rows/wave: 1 call
    const short* Bg = Wt + (n0 + wave * 16 + lr) * Cdim + lc * 8;   // 16 B-rows/wave: 1 call
    // prologue: stage batches 0 and 1 (2 loads each, in order)
    g2l16(Ag,       &As[0][wave * 512]);
    g2l16(Bg,       &Bs[0][wave * 512]);
    g2l16(Ag + 32,  &As[1][wave * 512]);
    g2l16(Bg + 32,  &Bs[1][wave * 512]);
    for (int kk = 0; kk < 16; kk++) {
        const int cur = kk & 1;
        if (kk < 15) { asm volatile("s_waitcnt vmcnt(2)" ::: "memory"); }   // oldest batch landed
        else         { asm volatile("s_waitcnt vmcnt(0)" ::: "memory"); }
        __builtin_amdgcn_s_barrier();              // buf[cur] ready across all waves
        __builtin_amdgcn_sched_barrier(0);
        bf16x8 a[2], w[2];
#pragma unroll
        for (int mt = 0; mt < 2; mt++) a[mt] = *(const bf16x8*)(&As[cur][(wm * 32 + mt * 16 + l15) * 32 + quad * 8]);
#pragma unroll
        for (int nt = 0; nt < 2; nt++) w[nt] = *(const bf16x8*)(&Bs[cur][(wn * 32 + nt * 16 + l15) * 32 + quad * 8]);
#pragma unroll
        for (int mt = 0; mt < 2; mt++)
#pragma unroll
            for (int nt = 0; nt < 2; nt++)
                acc[mt][nt] = __builtin_amdgcn_mfma_f32_16x16x32_bf16(a[mt], w[nt], acc[mt][nt], 0, 0, 0);
        __builtin_amdgcn_sched_barrier(0);
        __builtin_amdgcn_s_barrier();              // all waves done reading buf[cur]
        if (kk + 2 < 16) {                         // refill the just-freed buffer
            const int k0 = (kk + 2) * 32;
            g2l16(Ag + k0, &As[cur][wave * 512]);
            g2l16(Bg + k0, &Bs[cur][wave * 512]);
        }
    }
    const int m0w = m0 + wm * 32, n0w = n0 + wn * 32;
#pragma unroll
    for (int mt = 0; mt < 2; mt++) {
#pragma unroll
        for (int r = 0; r < 4; r++) {
            int t = m0w + mt * 16 + quad * 4 + r;
#pragma unroll
            for (int nt = 0; nt < 2; nt++) {
                int n = n0w + nt * 16 + l15;
                float fv = acc[mt][nt][r] + bias[n];
                fv = fmaxf(fv, 0.f);
                out[t * Cdim + n] = res[t * Cdim + n] + fv;
            }
        }
    }
}

extern "C" void kernel_launch(void* const* d_in, const int* in_sizes, int n_in,
                              void* d_out, int out_size, void* d_ws, size_t ws_size,
                              hipStream_t stream) {
    const float* x   = (const float*)d_in[0];
    const float* wq  = (const float*)d_in[1];
    const float* wk  = (const float*)d_in[2];
    const float* wv  = (const float*)d_in[3];
    const float* wff = (const float*)d_in[4];
    const float* bff = (const float*)d_in[5];
    const float* g1  = (const float*)d_in[6];
    const float* b1  = (const float*)d_in[7];
    const float* g2  = (const float*)d_in[8];
    const float* b2  = (const float*)d_in[9];

    char* p = (char*)d_ws;                                  // ~50 MB total scratch
    short* wqkvt = (short*)p; p += (size_t)NQKV * Cdim * 2;
    short* wfft  = (short*)p; p += (size_t)Cdim * Cdim * 2;
    short* h1    = (short*)p; p += (size_t)BT * Cdim * 2;   // reused as h2 after attention
    short* qb    = (short*)p; p += (size_t)BT * Cdim * 2;
    short* kb    = (short*)p; p += (size_t)BT * Cdim * 2;
    short* vtb   = (short*)p; p += (size_t)BT * Cdim * 2;
    float* out1  = (float*)p; p += (size_t)BT * Cdim * 4;

    hipLaunchKernelGGL(k_prep,     dim3(2304),    dim3(256), 0, stream,
                       wq, wk, wv, wff, wqkvt, wfft, x, g1, b1, h1);
    hipLaunchKernelGGL(k_gemm_qkv, dim3(64, 24),  dim3(256), 0, stream, h1, wqkvt, qb, kb, vtb);
    hipLaunchKernelGGL(k_attn,     dim3(32, 32),  dim3(256), 0, stream, qb, kb, vtb, x, out1);
    hipLaunchKernelGGL(k_ln,       dim3(2048),    dim3(256), 0, stream, out1, g2, b2, h1);
    hipLaunchKernelGGL(k_gemm_ff,  dim3(128, 8),  dim3(256), 0, stream, h1, wfft, bff, out1, (float*)d_out);
}